// Round 9
// baseline (392.656 us; speedup 1.0000x reference)
//
#include <hip/hip_runtime.h>
#include <hip/hip_fp16.h>
#include <math.h>

#define DEV __device__ __forceinline__

// Soft gate: c0 + ca*a + cb*b + cab*(a*b)
DEV float gev(float4 c, float a, float b) {
    return fmaf(c.w, a * b, fmaf(c.z, b, fmaf(c.y, a, c.x)));
}

// 16-byte fc gate record: fp16 coefs + u16 index pair
struct __align__(16) FcRec {
    __half2 c01, c23;   // {c0,ca}, {cb,cab}
    unsigned int idx;   // ia | ib<<16
    unsigned int pad;
};

// softmax over 16 op-logits -> affine coefficients {c0, ca, cb, cab}
DEV float4 softmax_coef(const float* __restrict__ wrow) {
    const float4* wv = (const float4*)wrow;
    float4 q0 = wv[0], q1 = wv[1], q2 = wv[2], q3 = wv[3];
    float p[16] = {q0.x,q0.y,q0.z,q0.w, q1.x,q1.y,q1.z,q1.w,
                   q2.x,q2.y,q2.z,q2.w, q3.x,q3.y,q3.z,q3.w};
    float mx = p[0];
    #pragma unroll
    for (int k = 1; k < 16; k++) mx = fmaxf(mx, p[k]);
    float s = 0.f;
    #pragma unroll
    for (int k = 0; k < 16; k++) { p[k] = __expf(p[k] - mx); s += p[k]; }
    float inv = 1.f / s;
    #pragma unroll
    for (int k = 0; k < 16; k++) p[k] *= inv;
    float c0  = p[8]+p[9]+p[10]+p[11]+p[12]+p[13]+p[14]+p[15];
    float ca  = p[2]+p[3]+p[6]+p[7]-p[8]-p[9]-p[12]-p[13];
    float cb  = p[4]+p[5]+p[6]+p[7]-p[8]-p[9]-p[10]-p[11];
    float cab = p[1]-p[2]-p[4]-2.f*p[6]-p[7]+p[8]+2.f*p[9]+p[11]+p[13]-p[14];
    return make_float4(c0, ca, cb, cab);
}

DEV float4 onehot4(int i) {
    return make_float4(i == 0 ? 1.f : 0.f, i == 1 ? 1.f : 0.f,
                       i == 2 ? 1.f : 0.f, i == 3 ? 1.f : 0.f);
}

// ---------------------------------------------------------------------------
// Pairwise sibling sync (WGs 2i / 2i+1 on one per-image counter).  Same
// device-scope fence pattern as the R3-verified grid barrier: release =
// threadfence (L2 writeback) + ACQ_REL add; acquire = spin + threadfence
// (cache invalidate).  No global straggler alignment.
// ---------------------------------------------------------------------------
DEV void pairsync(int* flag, int target) {
    __syncthreads();
    if (threadIdx.x == 0) {
        __threadfence();
        __hip_atomic_fetch_add(flag, 1, __ATOMIC_ACQ_REL, __HIP_MEMORY_SCOPE_AGENT);
        while (__hip_atomic_load(flag, __ATOMIC_ACQUIRE, __HIP_MEMORY_SCOPE_AGENT) < target)
            __builtin_amdgcn_s_sleep(1);
    }
    __syncthreads();
    __threadfence();
}

// ---------------------------------------------------------------------------
// setup_kernel: packs network + zeroes per-image pair flags.
//   [0,20480) fc1 | [20480,30720) fc2 | [30720,35840) fc3 : 16B FcRec
//   [35840,36048): conv filter 224B f32 records
// ---------------------------------------------------------------------------
__global__ __launch_bounds__(256) void setup_kernel(
    const int* __restrict__ c1i0, const int* __restrict__ c1i1, const int* __restrict__ c1i2,
    const int* __restrict__ c2i0, const int* __restrict__ c2i1, const int* __restrict__ c2i2,
    const int* __restrict__ c3i0, const int* __restrict__ c3i1, const int* __restrict__ c3i2,
    const float* __restrict__ c1w0, const float* __restrict__ c1w1, const float* __restrict__ c1w2,
    const float* __restrict__ c2w0, const float* __restrict__ c2w1, const float* __restrict__ c2w2,
    const float* __restrict__ c3w0, const float* __restrict__ c3w1, const float* __restrict__ c3w2,
    const int* __restrict__ fc1i, const float* __restrict__ fc1w,
    const int* __restrict__ fc2i, const float* __restrict__ fc2w,
    const int* __restrict__ fc3i, const float* __restrict__ fc3w,
    FcRec* __restrict__ fcp1, FcRec* __restrict__ fcp2, FcRec* __restrict__ fcp3,
    float4* __restrict__ cvp, int* __restrict__ flags)
{
    int t = blockIdx.x * 256 + threadIdx.x;
    if (t < 1600) flags[t] = 0;          // 100 images x 16-int stride
    if (t >= 36048) return;
    if (t < 35840) {
        const float* w; const int* idx; FcRec* dst; int o, D;
        if (t < 20480)      { o = t;         D = 20480; w = fc1w; idx = fc1i; dst = fcp1; }
        else if (t < 30720) { o = t - 20480; D = 10240; w = fc2w; idx = fc2i; dst = fcp2; }
        else                { o = t - 30720; D = 5120;  w = fc3w; idx = fc3i; dst = fcp3; }
        float4 cf = softmax_coef(w + o * 16);
        FcRec r;
        r.c01 = __half2(__float2half_rn(cf.x), __float2half_rn(cf.y));
        r.c23 = __half2(__float2half_rn(cf.z), __float2half_rn(cf.w));
        r.idx = ((unsigned)idx[o] & 0xffffu) | ((unsigned)idx[D + o] << 16);
        r.pad = 0;
        dst[o] = r;
        return;
    }
    int f = t - 35840;               // 0..207
    const int *i0, *i1, *i2; const float *W0, *W1, *W2;
    int F, KS, mode, lf;
    if (f < 16)      { lf = f;      F = 16;  KS = 5; mode = 1;
                       i0 = c1i0; i1 = c1i1; i2 = c1i2; W0 = c1w0; W1 = c1w1; W2 = c1w2; }
    else if (f < 64) { lf = f - 16; F = 48;  KS = 3; mode = 2;
                       i0 = c2i0; i1 = c2i1; i2 = c2i2; W0 = c2w0; W1 = c2w1; W2 = c2w2; }
    else             { lf = f - 64; F = 144; KS = 3; mode = 3;
                       i0 = c3i0; i1 = c3i1; i2 = c3i2; W0 = c3w0; W1 = c3w1; W2 = c3w2; }
    float4* pk = cvp + f * 14;
    int offs[8];
    #pragma unroll
    for (int g = 0; g < 8; g++) {
        int tt = (g < 4) ? i0[lf * 4 + g] : i0[F * 4 + lf * 4 + (g - 4)];
        int kk = KS * KS;
        int c = tt / kk, r = tt - c * kk;
        int dy = r / KS, dx = r - dy * KS;
        int off;
        if (mode == 1)      off = dy * 28 + dx;              // XB 28x28
        else if (mode == 2) off = (c * 14 + dy) * 14 + dx;   // P1 16x14x14 padded
        else                off = (c * 8 + dy) * 8 + dx;     // P2 48x8x8 padded
        offs[g] = off;
    }
    ((int4*)pk)[0] = make_int4(offs[0], offs[1], offs[2], offs[3]);
    ((int4*)pk)[1] = make_int4(offs[4], offs[5], offs[6], offs[7]);
    #pragma unroll
    for (int g = 0; g < 4; g++) pk[2 + g] = softmax_coef(W0 + (lf * 4 + g) * 16);
    pk[6] = onehot4(i1[lf * 2 + 0]);
    pk[7] = onehot4(i1[F * 2 + lf * 2 + 0]);
    pk[8] = onehot4(i1[lf * 2 + 1]);
    pk[9] = onehot4(i1[F * 2 + lf * 2 + 1]);
    pk[10] = softmax_coef(W1 + (lf * 2 + 0) * 16);
    pk[11] = softmax_coef(W1 + (lf * 2 + 1) * 16);
    int a2 = i2[lf], b2 = i2[F + lf];
    pk[12] = make_float4(a2 == 0 ? 1.f : 0.f, a2 == 1 ? 1.f : 0.f,
                         b2 == 0 ? 1.f : 0.f, b2 == 1 ? 1.f : 0.f);
    pk[13] = softmax_coef(W2 + lf * 16);
}

// ---------------------------------------------------------------------------
// Conv half-stage: filters [f0, f0+NF).  Writes own half to padded LDS
// (absolute f) AND compact global (G[f*HP*HP + p]) for the sibling.
// ---------------------------------------------------------------------------
template <int PITCH, int HP, int OUTP, int NF>
DEV void conv_half(const float* Sin, float* SoutL, float* __restrict__ SoutG,
                   const float4* __restrict__ pack, int f0, int tid)
{
    constexpr int N = NF * HP * HP;
    for (int t = tid; t < N; t += 1024) {
        int fl = t / (HP * HP);
        int p  = t - fl * (HP * HP);
        int f  = f0 + fl;
        int ph = p / HP, pw = p - ph * HP;
        const float4* pk = pack + f * 14;
        int4 ao = ((const int4*)pk)[0];
        int4 bo = ((const int4*)pk)[1];
        int base0 = 2 * ph * PITCH + 2 * pw;
        int offs[8] = {ao.x, ao.y, ao.z, ao.w, bo.x, bo.y, bo.z, bo.w};
        float v[8][4];
        #pragma unroll
        for (int g = 0; g < 8; g++) {
            const float* q = Sin + offs[g] + base0;
            v[g][0] = q[0];
            v[g][1] = q[1];
            v[g][2] = q[PITCH];
            v[g][3] = q[PITCH + 1];
        }
        float4 C00 = pk[2], C01 = pk[3], C02 = pk[4], C03 = pk[5];
        float4 oA0 = pk[6], oB0 = pk[7], oA1 = pk[8], oB1 = pk[9];
        float4 C10 = pk[10], C11 = pk[11], S2 = pk[12], C2 = pk[13];
        float m = -1e30f;
        #pragma unroll
        for (int q = 0; q < 4; q++) {
            float h00 = gev(C00, v[0][q], v[4][q]);
            float h01 = gev(C01, v[1][q], v[5][q]);
            float h02 = gev(C02, v[2][q], v[6][q]);
            float h03 = gev(C03, v[3][q], v[7][q]);
            float sa0 = fmaf(oA0.x, h00, fmaf(oA0.y, h01, fmaf(oA0.z, h02, oA0.w * h03)));
            float sb0 = fmaf(oB0.x, h00, fmaf(oB0.y, h01, fmaf(oB0.z, h02, oB0.w * h03)));
            float sa1 = fmaf(oA1.x, h00, fmaf(oA1.y, h01, fmaf(oA1.z, h02, oA1.w * h03)));
            float sb1 = fmaf(oB1.x, h00, fmaf(oB1.y, h01, fmaf(oB1.z, h02, oB1.w * h03)));
            float h10 = gev(C10, sa0, sb0);
            float h11 = gev(C11, sa1, sb1);
            float vv = gev(C2, fmaf(S2.x, h10, S2.y * h11),
                               fmaf(S2.z, h10, S2.w * h11));
            m = fmaxf(m, vv);
        }
        if (OUTP)
            SoutL[(f * OUTP + ph + 1) * OUTP + (pw + 1)] = m;
        else
            SoutL[f * HP * HP + p] = m;
        SoutG[f * HP * HP + p] = m;
    }
}

// Stage sibling's compact global half into the padded LDS tile.
template <int HP, int OUTP, int NF>
DEV void stage_pad(const float* __restrict__ G, float* L, int f0, int tid)
{
    constexpr int N = NF * HP * HP;
    for (int t = tid; t < N; t += 1024) {
        int fl = t / (HP * HP);
        int p  = t - fl * (HP * HP);
        int f  = f0 + fl;
        int ph = p / HP, pw = p - ph * HP;
        L[(f * OUTP + ph + 1) * OUTP + (pw + 1)] = G[f * HP * HP + p];
    }
}

// ---------------------------------------------------------------------------
// FC half-stage: DOUT outputs for this WG; dual store (global for sibling,
// LDS for self).  DOUT/1024 = CH (single chunk).
// ---------------------------------------------------------------------------
template <int DOUT, int CH, typename TIN>
DEV void fc_dual(const TIN* Sin, __half* __restrict__ Dg, __half* Dl,
                 const FcRec* __restrict__ pk, int tid)
{
    constexpr int K = DOUT / 1024;
    #pragma unroll 1
    for (int k0 = 0; k0 < K; k0 += CH) {
        FcRec r[CH];
        #pragma unroll
        for (int j = 0; j < CH; j++) r[j] = pk[tid + (k0 + j) * 1024];
        float va[CH], vb[CH];
        #pragma unroll
        for (int j = 0; j < CH; j++) {
            unsigned ii = r[j].idx;
            va[j] = (float)Sin[ii & 0xffffu];
            vb[j] = (float)Sin[ii >> 16];
        }
        #pragma unroll
        for (int j = 0; j < CH; j++) {
            float2 c01 = __half22float2(r[j].c01);
            float2 c23 = __half22float2(r[j].c23);
            float4 c = make_float4(c01.x, c01.y, c23.x, c23.y);
            __half v = __float2half(gev(c, va[j], vb[j]));
            Dg[tid + (k0 + j) * 1024] = v;
            Dl[tid + (k0 + j) * 1024] = v;
        }
    }
}

// ---------------------------------------------------------------------------
// mega_kernel: grid 200 = sibling pair (2i, 2i+1) per image, 1024 threads.
// All stages split 50/50 across the pair; halves exchanged via compact global
// buffers with pairwise flag syncs (no grid barriers).
// LDS (66624 B, lifetime-aliased):
//   F1s  @0     40960B (fc1 out / fc2 in)   } conv aliases: P2p @0 (12288),
//   F2s  @40960 20480B (fc2 out / fc3 in)   }   P1p @12544 (12544), XB @25600
//   P3s  @61440  5184B (conv out / fc1 in)  }   (3136) -- all dead by fc1
// ---------------------------------------------------------------------------
__global__ __launch_bounds__(1024, 4) void mega_kernel(
    const float* __restrict__ x, const float4* __restrict__ cvp,
    const FcRec* __restrict__ fcp1, const FcRec* __restrict__ fcp2,
    const FcRec* __restrict__ fcp3,
    float* __restrict__ P1g, float* __restrict__ P2g, float* __restrict__ P3g,
    __half* __restrict__ F1g, __half* __restrict__ F2g,
    int* __restrict__ flags, float* __restrict__ out)
{
    __shared__ __align__(16) char S[66624];
    __shared__ float red[48];
    __half* F1s = (__half*)S;
    float*  P2p = (float*)S;
    float*  P1p = (float*)(S + 12544);
    float*  XB  = (float*)(S + 25600);
    __half* F2s = (__half*)(S + 40960);
    float*  P3s = (float*)(S + 61440);

    const int tid = threadIdx.x;
    const int i = blockIdx.x >> 1, h = blockIdx.x & 1;
    int* flag = flags + i * 16;

    // init: binarize input, zero padded conv tiles (pads stay 0 throughout)
    if (tid < 784) XB[tid] = x[i * 784 + tid] > 0.5f ? 1.f : 0.f;
    if (tid < 784) ((float4*)P1p)[tid] = make_float4(0.f, 0.f, 0.f, 0.f);
    if (tid < 768) ((float4*)P2p)[tid] = make_float4(0.f, 0.f, 0.f, 0.f);
    __syncthreads();

    // conv stage 1: filters [h*8, h*8+8) of 16
    conv_half<28, 12, 14, 8>(XB, P1p, P1g + i * 2304, cvp, h * 8, tid);
    pairsync(flag, 2);
    stage_pad<12, 14, 8>(P1g + i * 2304, P1p, (1 - h) * 8, tid);
    __syncthreads();

    // conv stage 2: filters [h*24, +24) of 48
    conv_half<14, 6, 8, 24>(P1p, P2p, P2g + i * 1728, cvp + 16 * 14, h * 24, tid);
    pairsync(flag, 4);
    stage_pad<6, 8, 24>(P2g + i * 1728, P2p, (1 - h) * 24, tid);
    __syncthreads();

    // conv stage 3: filters [h*72, +72) of 144, unpadded out
    conv_half<8, 3, 0, 72>(P2p, P3s, P3g + i * 1296, cvp + 64 * 14, h * 72, tid);
    pairsync(flag, 6);
    {   // sibling P3 half: 648 floats, linear copy
        int o = (1 - h) * 648;
        for (int k = tid; k < 648; k += 1024) P3s[o + k] = P3g[i * 1296 + o + k];
    }
    __syncthreads();

    // fc1: outputs [h*10240, +10240); own half to LDS+global
    fc_dual<10240, 10, float>(P3s, F1g + i * 20480 + h * 10240,
                              F1s + h * 10240, fcp1 + h * 10240, tid);
    pairsync(flag, 8);
    {   // sibling F1 half: 20480B = 1280 int4
        int o4 = (1 - h) * 1280;
        const int4* src = (const int4*)(F1g + i * 20480);
        int4* dst = (int4*)F1s;
        for (int k = tid; k < 1280; k += 1024) dst[o4 + k] = src[o4 + k];
    }
    __syncthreads();

    // fc2: outputs [h*5120, +5120)
    fc_dual<5120, 5, __half>(F1s, F2g + i * 10240 + h * 5120,
                             F2s + h * 5120, fcp2 + h * 5120, tid);
    pairsync(flag, 10);
    {   // sibling F2 half: 10240B = 640 int4
        int o4 = (1 - h) * 640;
        const int4* src = (const int4*)(F2g + i * 10240);
        int4* dst = (int4*)F2s;
        for (int k = tid; k < 640; k += 1024) dst[o4 + k] = src[o4 + k];
    }
    __syncthreads();

    // fc3 + GroupSum: gates [h*2560, +2560) = groups [h*5, h*5+5)
    {
        const FcRec* pk = fcp3 + h * 2560;
        int wave = tid >> 6, lane = tid & 63;
        #pragma unroll
        for (int j = 0; j < 3; j++) {
            int l = j * 1024 + tid;
            if (l < 2560) {
                FcRec r = pk[l];
                float va = __half2float(F2s[r.idx & 0xffffu]);
                float vb = __half2float(F2s[r.idx >> 16]);
                float2 c01 = __half22float2(r.c01), c23 = __half22float2(r.c23);
                float v = gev(make_float4(c01.x, c01.y, c23.x, c23.y), va, vb);
                #pragma unroll
                for (int off = 32; off > 0; off >>= 1) v += __shfl_down(v, off, 64);
                if (lane == 0) red[j * 16 + wave] = v;   // group = 2j + wave/8
            }
        }
        __syncthreads();
        if (tid < 5) {
            int jj = tid >> 1, wb = (tid & 1) * 8;
            float s = 0.f;
            #pragma unroll
            for (int k2 = 0; k2 < 8; k2++) s += red[jj * 16 + wb + k2];
            out[i * 10 + h * 5 + tid] = s * (1.f / 30.f);
        }
    }
}

extern "C" void kernel_launch(void* const* d_in, const int* in_sizes, int n_in,
                              void* d_out, int out_size, void* d_ws, size_t ws_size,
                              hipStream_t stream)
{
    const float* x     = (const float*)d_in[0];
    const int*   c1i0  = (const int*)d_in[1];  const float* c1w0 = (const float*)d_in[2];
    const int*   c1i1  = (const int*)d_in[3];  const float* c1w1 = (const float*)d_in[4];
    const int*   c1i2  = (const int*)d_in[5];  const float* c1w2 = (const float*)d_in[6];
    const int*   c2i0  = (const int*)d_in[7];  const float* c2w0 = (const float*)d_in[8];
    const int*   c2i1  = (const int*)d_in[9];  const float* c2w1 = (const float*)d_in[10];
    const int*   c2i2  = (const int*)d_in[11]; const float* c2w2 = (const float*)d_in[12];
    const int*   c3i0  = (const int*)d_in[13]; const float* c3w0 = (const float*)d_in[14];
    const int*   c3i1  = (const int*)d_in[15]; const float* c3w1 = (const float*)d_in[16];
    const int*   c3i2  = (const int*)d_in[17]; const float* c3w2 = (const float*)d_in[18];
    const int*   fc1i  = (const int*)d_in[19]; const float* fc1w = (const float*)d_in[20];
    const int*   fc2i  = (const int*)d_in[21]; const float* fc2w = (const float*)d_in[22];
    const int*   fc3i  = (const int*)d_in[23]; const float* fc3w = (const float*)d_in[24];

    // ws layout:
    //   fcp1  @0        (327680)
    //   fcp2  @327680   (163840)
    //   fcp3  @491520   (81920)
    //   cvp   @573440   (46592)   end 620032
    //   flags @620032   (6400)    end 626432   (100 x 16 ints)
    //   P1g   @626432   (100*2304*4 = 921600)  end 1548032
    //   P2g   @1548032  (100*1728*4 = 691200)  end 2239232
    //   P3g   @2239232  (100*1296*4 = 518400)  end 2757632
    //   F1g   @2757632  (100*20480*2 = 4096000) end 6853632
    //   F2g   @6853632  (100*10240*2 = 2048000) end 8901632
    char* ws = (char*)d_ws;
    FcRec*  fcp1  = (FcRec*)ws;
    FcRec*  fcp2  = (FcRec*)(ws + 327680);
    FcRec*  fcp3  = (FcRec*)(ws + 491520);
    float4* cvp   = (float4*)(ws + 573440);
    int*    flags = (int*)(ws + 620032);
    float*  P1g   = (float*)(ws + 626432);
    float*  P2g   = (float*)(ws + 1548032);
    float*  P3g   = (float*)(ws + 2239232);
    __half* F1g   = (__half*)(ws + 2757632);
    __half* F2g   = (__half*)(ws + 6853632);

    setup_kernel<<<141, 256, 0, stream>>>(
        c1i0, c1i1, c1i2, c2i0, c2i1, c2i2, c3i0, c3i1, c3i2,
        c1w0, c1w1, c1w2, c2w0, c2w1, c2w2, c3w0, c3w1, c3w2,
        fc1i, fc1w, fc2i, fc2w, fc3i, fc3w,
        fcp1, fcp2, fcp3, cvp, flags);

    mega_kernel<<<200, 1024, 0, stream>>>(
        x, cvp, fcp1, fcp2, fcp3, P1g, P2g, P3g, F1g, F2g,
        flags, (float*)d_out);
}

// Round 11
// 290.027 us; speedup vs baseline: 1.3539x; 1.3539x over previous
//
#include <hip/hip_runtime.h>
#include <hip/hip_fp16.h>
#include <math.h>

#define DEV __device__ __forceinline__

// Soft gate: c0 + ca*a + cb*b + cab*(a*b)
DEV float gev(float4 c, float a, float b) {
    return fmaf(c.w, a * b, fmaf(c.z, b, fmaf(c.y, a, c.x)));
}

// 16-byte fc gate record: fp16 coefs + u16 index pair
struct __align__(16) FcRec {
    __half2 c01, c23;   // {c0,ca}, {cb,cab}
    unsigned int idx;   // ia | ib<<16
    unsigned int pad;
};

// softmax over 16 op-logits -> affine coefficients {c0, ca, cb, cab}
DEV float4 softmax_coef(const float* __restrict__ wrow) {
    const float4* wv = (const float4*)wrow;
    float4 q0 = wv[0], q1 = wv[1], q2 = wv[2], q3 = wv[3];
    float p[16] = {q0.x,q0.y,q0.z,q0.w, q1.x,q1.y,q1.z,q1.w,
                   q2.x,q2.y,q2.z,q2.w, q3.x,q3.y,q3.z,q3.w};
    float mx = p[0];
    #pragma unroll
    for (int k = 1; k < 16; k++) mx = fmaxf(mx, p[k]);
    float s = 0.f;
    #pragma unroll
    for (int k = 0; k < 16; k++) { p[k] = __expf(p[k] - mx); s += p[k]; }
    float inv = 1.f / s;
    #pragma unroll
    for (int k = 0; k < 16; k++) p[k] *= inv;
    float c0  = p[8]+p[9]+p[10]+p[11]+p[12]+p[13]+p[14]+p[15];
    float ca  = p[2]+p[3]+p[6]+p[7]-p[8]-p[9]-p[12]-p[13];
    float cb  = p[4]+p[5]+p[6]+p[7]-p[8]-p[9]-p[10]-p[11];
    float cab = p[1]-p[2]-p[4]-2.f*p[6]-p[7]+p[8]+2.f*p[9]+p[11]+p[13]-p[14];
    return make_float4(c0, ca, cb, cab);
}

DEV float4 onehot4(int i) {
    return make_float4(i == 0 ? 1.f : 0.f, i == 1 ? 1.f : 0.f,
                       i == 2 ? 1.f : 0.f, i == 3 ? 1.f : 0.f);
}

// ---------------------------------------------------------------------------
// Pair-local sync: WGs 2i / 2i+1 meet on one per-image counter.  Same fence
// mechanics as the R3-verified grid barrier (release = threadfence + ACQ_REL
// add; acquire = spin + threadfence); only the participant set shrinks from
// 200 WGs to the sibling pair, removing chip-wide straggler alignment.
// ---------------------------------------------------------------------------
DEV void pairsync(int* flag, int target) {
    __syncthreads();
    if (threadIdx.x == 0) {
        __threadfence();
        __hip_atomic_fetch_add(flag, 1, __ATOMIC_ACQ_REL, __HIP_MEMORY_SCOPE_AGENT);
        while (__hip_atomic_load(flag, __ATOMIC_ACQUIRE, __HIP_MEMORY_SCOPE_AGENT) < target)
            __builtin_amdgcn_s_sleep(1);
    }
    __syncthreads();
    __threadfence();
}

// ---------------------------------------------------------------------------
// setup_kernel: packs network + zeroes per-image pair flags.
//   [0,20480) fc1 | [20480,30720) fc2 | [30720,35840) fc3 : 16B FcRec
//   [35840,36048): conv filter 224B f32 records
// ---------------------------------------------------------------------------
__global__ __launch_bounds__(256) void setup_kernel(
    const int* __restrict__ c1i0, const int* __restrict__ c1i1, const int* __restrict__ c1i2,
    const int* __restrict__ c2i0, const int* __restrict__ c2i1, const int* __restrict__ c2i2,
    const int* __restrict__ c3i0, const int* __restrict__ c3i1, const int* __restrict__ c3i2,
    const float* __restrict__ c1w0, const float* __restrict__ c1w1, const float* __restrict__ c1w2,
    const float* __restrict__ c2w0, const float* __restrict__ c2w1, const float* __restrict__ c2w2,
    const float* __restrict__ c3w0, const float* __restrict__ c3w1, const float* __restrict__ c3w2,
    const int* __restrict__ fc1i, const float* __restrict__ fc1w,
    const int* __restrict__ fc2i, const float* __restrict__ fc2w,
    const int* __restrict__ fc3i, const float* __restrict__ fc3w,
    FcRec* __restrict__ fcp1, FcRec* __restrict__ fcp2, FcRec* __restrict__ fcp3,
    float4* __restrict__ cvp, int* __restrict__ flags)
{
    int t = blockIdx.x * 256 + threadIdx.x;
    if (t < 1600) flags[t] = 0;          // 100 images x 16-int stride
    if (t >= 36048) return;
    if (t < 35840) {
        const float* w; const int* idx; FcRec* dst; int o, D;
        if (t < 20480)      { o = t;         D = 20480; w = fc1w; idx = fc1i; dst = fcp1; }
        else if (t < 30720) { o = t - 20480; D = 10240; w = fc2w; idx = fc2i; dst = fcp2; }
        else                { o = t - 30720; D = 5120;  w = fc3w; idx = fc3i; dst = fcp3; }
        float4 cf = softmax_coef(w + o * 16);
        FcRec r;
        r.c01 = __half2(__float2half_rn(cf.x), __float2half_rn(cf.y));
        r.c23 = __half2(__float2half_rn(cf.z), __float2half_rn(cf.w));
        r.idx = ((unsigned)idx[o] & 0xffffu) | ((unsigned)idx[D + o] << 16);
        r.pad = 0;
        dst[o] = r;
        return;
    }
    int f = t - 35840;               // 0..207
    const int *i0, *i1, *i2; const float *W0, *W1, *W2;
    int F, KS, mode, lf;
    if (f < 16)      { lf = f;      F = 16;  KS = 5; mode = 1;
                       i0 = c1i0; i1 = c1i1; i2 = c1i2; W0 = c1w0; W1 = c1w1; W2 = c1w2; }
    else if (f < 64) { lf = f - 16; F = 48;  KS = 3; mode = 2;
                       i0 = c2i0; i1 = c2i1; i2 = c2i2; W0 = c2w0; W1 = c2w1; W2 = c2w2; }
    else             { lf = f - 64; F = 144; KS = 3; mode = 3;
                       i0 = c3i0; i1 = c3i1; i2 = c3i2; W0 = c3w0; W1 = c3w1; W2 = c3w2; }
    float4* pk = cvp + f * 14;
    int offs[8];
    #pragma unroll
    for (int g = 0; g < 8; g++) {
        int tt = (g < 4) ? i0[lf * 4 + g] : i0[F * 4 + lf * 4 + (g - 4)];
        int kk = KS * KS;
        int c = tt / kk, r = tt - c * kk;
        int dy = r / KS, dx = r - dy * KS;
        int off;
        if (mode == 1)      off = dy * 28 + dx;              // XB 28x28
        else if (mode == 2) off = (c * 14 + dy) * 14 + dx;   // P1 16x14x14 padded
        else                off = (c * 8 + dy) * 8 + dx;     // P2 48x8x8 padded
        offs[g] = off;
    }
    ((int4*)pk)[0] = make_int4(offs[0], offs[1], offs[2], offs[3]);
    ((int4*)pk)[1] = make_int4(offs[4], offs[5], offs[6], offs[7]);
    #pragma unroll
    for (int g = 0; g < 4; g++) pk[2 + g] = softmax_coef(W0 + (lf * 4 + g) * 16);
    pk[6] = onehot4(i1[lf * 2 + 0]);
    pk[7] = onehot4(i1[F * 2 + lf * 2 + 0]);
    pk[8] = onehot4(i1[lf * 2 + 1]);
    pk[9] = onehot4(i1[F * 2 + lf * 2 + 1]);
    pk[10] = softmax_coef(W1 + (lf * 2 + 0) * 16);
    pk[11] = softmax_coef(W1 + (lf * 2 + 1) * 16);
    int a2 = i2[lf], b2 = i2[F + lf];
    pk[12] = make_float4(a2 == 0 ? 1.f : 0.f, a2 == 1 ? 1.f : 0.f,
                         b2 == 0 ? 1.f : 0.f, b2 == 1 ? 1.f : 0.f);
    pk[13] = softmax_coef(W2 + lf * 16);
}

// ---------------------------------------------------------------------------
// Conv stage: per input offset one base pointer with offsets {0,1,PITCH,PITCH+1}.
// (R3-verbatim: compiles to 128-VGPR resident-operand code.)
// ---------------------------------------------------------------------------
template <int PITCH, int HP, int F, int OUTP>
DEV void conv_stage(const float* Sin, float* Sout, const float4* __restrict__ pack,
                    int tid)
{
    constexpr int N = F * HP * HP;
    for (int t = tid; t < N; t += 1024) {
        int f  = t / (HP * HP);
        int p  = t - f * (HP * HP);
        int ph = p / HP, pw = p - ph * HP;
        const float4* pk = pack + f * 14;
        int4 ao = ((const int4*)pk)[0];
        int4 bo = ((const int4*)pk)[1];
        int base0 = 2 * ph * PITCH + 2 * pw;
        int offs[8] = {ao.x, ao.y, ao.z, ao.w, bo.x, bo.y, bo.z, bo.w};
        float v[8][4];
        #pragma unroll
        for (int g = 0; g < 8; g++) {
            const float* q = Sin + offs[g] + base0;
            v[g][0] = q[0];
            v[g][1] = q[1];
            v[g][2] = q[PITCH];
            v[g][3] = q[PITCH + 1];
        }
        float4 C00 = pk[2], C01 = pk[3], C02 = pk[4], C03 = pk[5];
        float4 oA0 = pk[6], oB0 = pk[7], oA1 = pk[8], oB1 = pk[9];
        float4 C10 = pk[10], C11 = pk[11], S2 = pk[12], C2 = pk[13];
        float m = -1e30f;
        #pragma unroll
        for (int q = 0; q < 4; q++) {
            float h00 = gev(C00, v[0][q], v[4][q]);
            float h01 = gev(C01, v[1][q], v[5][q]);
            float h02 = gev(C02, v[2][q], v[6][q]);
            float h03 = gev(C03, v[3][q], v[7][q]);
            float sa0 = fmaf(oA0.x, h00, fmaf(oA0.y, h01, fmaf(oA0.z, h02, oA0.w * h03)));
            float sb0 = fmaf(oB0.x, h00, fmaf(oB0.y, h01, fmaf(oB0.z, h02, oB0.w * h03)));
            float sa1 = fmaf(oA1.x, h00, fmaf(oA1.y, h01, fmaf(oA1.z, h02, oA1.w * h03)));
            float sb1 = fmaf(oB1.x, h00, fmaf(oB1.y, h01, fmaf(oB1.z, h02, oB1.w * h03)));
            float h10 = gev(C10, sa0, sb0);
            float h11 = gev(C11, sa1, sb1);
            float vv = gev(C2, fmaf(S2.x, h10, S2.y * h11),
                               fmaf(S2.z, h10, S2.w * h11));
            m = fmaxf(m, vv);
        }
        if (OUTP)
            Sout[(f * OUTP + ph + 1) * OUTP + (pw + 1)] = m;
        else
            Sout[t] = m;
    }
}

// ---------------------------------------------------------------------------
// FC stage with 16B records, chunk-of-CH pipeline.  DOUT % (1024*CH) == 0.
// (R3-verbatim.)
// ---------------------------------------------------------------------------
template <int DOUT, int CH, typename TIN, typename TOUT>
DEV void fc_stage(const TIN* Sin, TOUT* Sout, const FcRec* __restrict__ pk, int tid)
{
    constexpr int K = DOUT / 1024;
    #pragma unroll 1
    for (int k0 = 0; k0 < K; k0 += CH) {
        FcRec r[CH];
        #pragma unroll
        for (int j = 0; j < CH; j++) r[j] = pk[tid + (k0 + j) * 1024];
        float va[CH], vb[CH];
        #pragma unroll
        for (int j = 0; j < CH; j++) {
            unsigned ii = r[j].idx;
            va[j] = (float)Sin[ii & 0xffffu];
            vb[j] = (float)Sin[ii >> 16];
        }
        #pragma unroll
        for (int j = 0; j < CH; j++) {
            float2 c01 = __half22float2(r[j].c01);
            float2 c23 = __half22float2(r[j].c23);
            float4 c = make_float4(c01.x, c01.y, c23.x, c23.y);
            Sout[tid + (k0 + j) * 1024] = (TOUT)gev(c, va[j], vb[j]);
        }
    }
}

// ---------------------------------------------------------------------------
// mega_kernel: R3 structure verbatim (grid 200 = 2 WGs per image, 1024 thr):
//   phase 0: conv chain (h==0 WGs only) -> P3g
//   pairsync(2) ; phase 1: fc1 (2 WGs/image, 10240 outs each) -> F1g
//   pairsync(4) ; phase 2: fc2 (5120 outs each)               -> F2g
//   pairsync(6) ; phase 3: fc3 (2560 outs each) + GroupSum    -> out
// ONLY change vs R3: grid barriers -> pair-local syncs (deps are pair-local).
// LDS: one 40960B buffer reused per phase (max = fc2's 40KB F1 stage).
// ---------------------------------------------------------------------------
__global__ __launch_bounds__(1024, 4) void mega_kernel(
    const float* __restrict__ x, const float4* __restrict__ cvp,
    const FcRec* __restrict__ fcp1, const FcRec* __restrict__ fcp2,
    const FcRec* __restrict__ fcp3, float* __restrict__ P3g,
    __half* __restrict__ F1g, __half* __restrict__ F2g,
    int* __restrict__ flags, float* __restrict__ out)
{
    __shared__ __align__(16) char S[40960];
    __shared__ float red[48];
    const int tid = threadIdx.x;
    const int i = blockIdx.x >> 1, h = blockIdx.x & 1;
    int* flag = flags + i * 16;

    if (h == 0) {
        // conv chain in LDS: P1p @0 (12544B) | XB @12544 (3136B) | P2p @15680 (12288B)
        float* P1p = (float*)S;
        float* XB  = (float*)(S + 12544);
        float* P2p = (float*)(S + 15680);
        if (tid < 784) XB[tid] = x[i * 784 + tid] > 0.5f ? 1.f : 0.f;
        if (tid < 784) ((float4*)P1p)[tid] = make_float4(0.f, 0.f, 0.f, 0.f);
        if (tid < 768) ((float4*)P2p)[tid] = make_float4(0.f, 0.f, 0.f, 0.f);
        __syncthreads();
        conv_stage<28, 12, 16, 14>(XB, P1p, cvp + 0 * 14, tid);
        __syncthreads();
        conv_stage<14, 6, 48, 8>(P1p, P2p, cvp + 16 * 14, tid);
        __syncthreads();
        conv_stage<8, 3, 144, 0>(P2p, P3g + i * 1296, cvp + 64 * 14, tid);
    }
    pairsync(flag, 2);

    // fc1: outputs [h*10240, (h+1)*10240) of image i
    {
        float* Sin = (float*)S;
        if (tid < 648) ((float2*)Sin)[tid] = ((const float2*)(P3g + i * 1296))[tid];
        __syncthreads();
        fc_stage<10240, 10, float, __half>(Sin, F1g + i * 20480 + h * 10240,
                                           fcp1 + h * 10240, tid);
    }
    pairsync(flag, 4);

    // fc2: stage full F1 (40KB), outputs [h*5120, (h+1)*5120)
    {
        __half* Sin = (__half*)S;
        const int4* src = (const int4*)(F1g + i * 20480);
        for (int k = tid; k < 2560; k += 1024) ((int4*)Sin)[k] = src[k];
        __syncthreads();
        fc_stage<5120, 5, __half, __half>(Sin, F2g + i * 10240 + h * 5120,
                                          fcp2 + h * 5120, tid);
    }
    pairsync(flag, 6);

    // fc3 + GroupSum: outputs [h*2560, (h+1)*2560) = groups [h*5, h*5+5)
    {
        __half* Sin = (__half*)S;
        const int4* src = (const int4*)(F2g + i * 10240);
        for (int k = tid; k < 1280; k += 1024) ((int4*)Sin)[k] = src[k];
        __syncthreads();
        const FcRec* pk = fcp3 + h * 2560;
        int wave = tid >> 6, lane = tid & 63;
        #pragma unroll
        for (int j = 0; j < 3; j++) {
            int l = j * 1024 + tid;
            if (l < 2560) {
                FcRec r = pk[l];
                float va = __half2float(Sin[r.idx & 0xffffu]);
                float vb = __half2float(Sin[r.idx >> 16]);
                float2 c01 = __half22float2(r.c01), c23 = __half22float2(r.c23);
                float v = gev(make_float4(c01.x, c01.y, c23.x, c23.y), va, vb);
                #pragma unroll
                for (int off = 32; off > 0; off >>= 1) v += __shfl_down(v, off, 64);
                if (lane == 0) red[j * 16 + wave] = v;   // group = 2j + wave/8
            }
        }
        __syncthreads();
        if (tid < 5) {
            int jj = tid >> 1, wb = (tid & 1) * 8;
            float s = 0.f;
            #pragma unroll
            for (int k2 = 0; k2 < 8; k2++) s += red[jj * 16 + wb + k2];
            out[i * 10 + h * 5 + tid] = s * (1.f / 30.f);
        }
    }
}

extern "C" void kernel_launch(void* const* d_in, const int* in_sizes, int n_in,
                              void* d_out, int out_size, void* d_ws, size_t ws_size,
                              hipStream_t stream)
{
    const float* x     = (const float*)d_in[0];
    const int*   c1i0  = (const int*)d_in[1];  const float* c1w0 = (const float*)d_in[2];
    const int*   c1i1  = (const int*)d_in[3];  const float* c1w1 = (const float*)d_in[4];
    const int*   c1i2  = (const int*)d_in[5];  const float* c1w2 = (const float*)d_in[6];
    const int*   c2i0  = (const int*)d_in[7];  const float* c2w0 = (const float*)d_in[8];
    const int*   c2i1  = (const int*)d_in[9];  const float* c2w1 = (const float*)d_in[10];
    const int*   c2i2  = (const int*)d_in[11]; const float* c2w2 = (const float*)d_in[12];
    const int*   c3i0  = (const int*)d_in[13]; const float* c3w0 = (const float*)d_in[14];
    const int*   c3i1  = (const int*)d_in[15]; const float* c3w1 = (const float*)d_in[16];
    const int*   c3i2  = (const int*)d_in[17]; const float* c3w2 = (const float*)d_in[18];
    const int*   fc1i  = (const int*)d_in[19]; const float* fc1w = (const float*)d_in[20];
    const int*   fc2i  = (const int*)d_in[21]; const float* fc2w = (const float*)d_in[22];
    const int*   fc3i  = (const int*)d_in[23]; const float* fc3w = (const float*)d_in[24];

    // ws layout (R3's, with bar -> flags region):
    //   fcp1  @0        (327680)
    //   fcp2  @327680   (163840)
    //   fcp3  @491520   (81920)
    //   cvp   @573440   (46592)  end 620032
    //   flags @620032   (6400)   end 626432   (100 x 16 ints)
    //   P3g   @2232896  (100*1296*4  = 518400)  end 2751296
    //   F1g   @2751296  (100*20480*2 = 4096000) end 6847296
    //   F2g   @6847296  (100*10240*2 = 2048000) end 8895296
    char* ws = (char*)d_ws;
    FcRec*  fcp1  = (FcRec*)ws;
    FcRec*  fcp2  = (FcRec*)(ws + 327680);
    FcRec*  fcp3  = (FcRec*)(ws + 491520);
    float4* cvp   = (float4*)(ws + 573440);
    int*    flags = (int*)(ws + 620032);
    float*  P3g   = (float*)(ws + 2232896);
    __half* F1g   = (__half*)(ws + 2751296);
    __half* F2g   = (__half*)(ws + 6847296);

    setup_kernel<<<141, 256, 0, stream>>>(
        c1i0, c1i1, c1i2, c2i0, c2i1, c2i2, c3i0, c3i1, c3i2,
        c1w0, c1w1, c1w2, c2w0, c2w1, c2w2, c3w0, c3w1, c3w2,
        fc1i, fc1w, fc2i, fc2w, fc3i, fc3w,
        fcp1, fcp2, fcp3, cvp, flags);

    mega_kernel<<<200, 1024, 0, stream>>>(
        x, cvp, fcp1, fcp2, fcp3, P3g, F1g, F2g, flags, (float*)d_out);
}